// Round 4
// baseline (279.273 us; speedup 1.0000x reference)
//
#include <hip/hip_runtime.h>

// DynamicOversizeConv2d: per (b,c) pair [2048 total], 96x96 matrices:
//   M_h = softmax_rows(Q K^T) + band_h(c);  M_w = softmax_rows(Q^T K) + band_w(c)
//   Out = (M_h V) M_w^T
// Inputs fp32, output fp32. Internal MFMA compute in FP16 (not bf16): fp16's
// 2^-11 roundoff keeps the softmax-amplified score error ~8x below bf16's,
// which was the round-3 failure (absmax 0.148 vs 0.119 threshold).
// One block per pair, 256 threads (4 waves), 16x16x32 f16 MFMA, 3x3 acc/wave.
// LDS = 4 f16 tiles (96x104) with liveness reuse + fp32 out-stage over the
// dead b2+b3 region + softmax scratch = 81,512 B -> 2 blocks/CU.

typedef unsigned short u16;
typedef unsigned int u32;
typedef __attribute__((ext_vector_type(8))) _Float16 half8;
typedef __attribute__((ext_vector_type(4))) float floatx4;

#define NN 96
#define LD 104            // f16-tile row pitch (elems): 208 B, 16B-aligned
#define OP 100            // fp32 out-stage row pitch (floats): 400 B
#define PAIRS 2048
#define IMG 9216          // 96*96
#define SMEM_BYTES 81512  // 4*96*104*2 + 2*192*4 + 26*4

__device__ __forceinline__ u16 f2h(float f) {
  union { _Float16 h; u16 u; } x;
  x.h = (_Float16)f;  // v_cvt_f16_f32, RNE
  return x.u;
}
__device__ __forceinline__ u32 pk(float lo, float hi) {
  return (u32)f2h(lo) | ((u32)f2h(hi) << 16);
}

// D[m,n] = sum_k A[m,k] * BT[n,k]; A,BT row-major f16 in LDS, pitch LD.
// Wave owns 3x3 tiles at (tr0, tc0). A/B frags: 8 contiguous f16 per lane.
__device__ __forceinline__ void mm33(const u16* A, const u16* B,
                                     int tr0, int tc0, int ln, int quad,
                                     floatx4 acc[3][3]) {
#pragma unroll
  for (int i = 0; i < 3; ++i)
#pragma unroll
    for (int j = 0; j < 3; ++j)
      acc[i][j] = (floatx4){0.f, 0.f, 0.f, 0.f};
#pragma unroll
  for (int ks = 0; ks < 3; ++ks) {
    const int kb = ks * 32 + quad * 8;
    half8 a[3], b[3];
#pragma unroll
    for (int i = 0; i < 3; ++i)
      a[i] = *(const half8*)(A + (tr0 + i * 16 + ln) * LD + kb);
#pragma unroll
    for (int j = 0; j < 3; ++j)
      b[j] = *(const half8*)(B + (tc0 + j * 16 + ln) * LD + kb);
#pragma unroll
    for (int i = 0; i < 3; ++i)
#pragma unroll
      for (int j = 0; j < 3; ++j)
        acc[i][j] = __builtin_amdgcn_mfma_f32_16x16x32_f16(a[i], b[j], acc[i][j], 0, 0, 0);
  }
}

// Row softmax of acc (rows split across wave pairs), + banded kernel, f16 -> D.
// C/D layout: row = quad*4 + v, col = lane&15 within each 16x16 tile.
__device__ __forceinline__ void softmax_band(floatx4 acc[3][3], int tr0, int tc0,
                                             int ln, int quad, int whalf,
                                             float* scrM, float* scrS,
                                             const float* band13, u16* D) {
  __syncthreads();  // all MFMA reads done before D (may alias A-source) is written
  float red[3][4];
#pragma unroll
  for (int i = 0; i < 3; ++i)
#pragma unroll
    for (int v = 0; v < 4; ++v) {
      float m = fmaxf(fmaxf(acc[i][0][v], acc[i][1][v]), acc[i][2][v]);
      m = fmaxf(m, __shfl_xor(m, 1));
      m = fmaxf(m, __shfl_xor(m, 2));
      m = fmaxf(m, __shfl_xor(m, 4));
      m = fmaxf(m, __shfl_xor(m, 8));
      red[i][v] = m;
    }
  if (ln == 0) {
#pragma unroll
    for (int i = 0; i < 3; ++i)
#pragma unroll
      for (int v = 0; v < 4; ++v)
        scrM[(tr0 + i * 16 + quad * 4 + v) * 2 + whalf] = red[i][v];
  }
  __syncthreads();
#pragma unroll
  for (int i = 0; i < 3; ++i)
#pragma unroll
    for (int v = 0; v < 4; ++v) {
      const int R = tr0 + i * 16 + quad * 4 + v;
      const float m = fmaxf(scrM[R * 2], scrM[R * 2 + 1]);
      float s = 0.f;
#pragma unroll
      for (int j = 0; j < 3; ++j) {
        float e = __expf(acc[i][j][v] - m);
        acc[i][j][v] = e;
        s += e;
      }
      s += __shfl_xor(s, 1);
      s += __shfl_xor(s, 2);
      s += __shfl_xor(s, 4);
      s += __shfl_xor(s, 8);
      red[i][v] = s;
    }
  if (ln == 0) {
#pragma unroll
    for (int i = 0; i < 3; ++i)
#pragma unroll
      for (int v = 0; v < 4; ++v)
        scrS[(tr0 + i * 16 + quad * 4 + v) * 2 + whalf] = red[i][v];
  }
  __syncthreads();
#pragma unroll
  for (int i = 0; i < 3; ++i)
#pragma unroll
    for (int v = 0; v < 4; ++v) {
      const int R = tr0 + i * 16 + quad * 4 + v;
      const float inv = __builtin_amdgcn_rcpf(scrS[R * 2] + scrS[R * 2 + 1]);
#pragma unroll
      for (int j = 0; j < 3; ++j) {
        const int C = tc0 + j * 16 + ln;
        const int off = C - R + 6;  // kernel[c, j-i+6] when 0<=off<13
        const float bnd = ((unsigned)off < 13u) ? band13[off] : 0.f;
        D[R * LD + C] = f2h(acc[i][j][v] * inv + bnd);
      }
    }
  __syncthreads();
}

extern "C" __global__ void __launch_bounds__(256, 2)
doc_kernel(const float* __restrict__ qg, const float* __restrict__ kg,
           const float* __restrict__ vg, const float* __restrict__ khg,
           const float* __restrict__ kwg, float* __restrict__ og) {
  extern __shared__ char smem[];
  u16* b0 = (u16*)smem;       // Q      -> M_h
  u16* b1 = b0 + NN * LD;     // K      -> M_w
  u16* b2 = b1 + NN * LD;     // Q^T    -> V^T -> (with b3) fp32 out stage
  u16* b3 = b2 + NN * LD;     // K^T    -> V1
  float* scrM = (float*)(b3 + NN * LD);  // [96][2]
  float* scrS = scrM + 192;              // [96][2]
  float* kh13 = scrS + 192;              // 13
  float* kw13 = kh13 + 13;               // 13
  float* ostage = (float*)b2;            // 96 x OP fp32 (38,400 B over b2+b3)

  const int pair = blockIdx.x;
  const int c = pair & 255;
  const int tid = threadIdx.x;
  const int lane = tid & 63;
  const int wv = tid >> 6;
  const int quad = lane >> 4;
  const int ln = lane & 15;
  const int tr0 = (wv >> 1) * 48;  // waves 0,1 rows 0-47; 2,3 rows 48-95
  const int tc0 = (wv & 1) * 48;   // waves 0,2 cols 0-47; 1,3 cols 48-95
  const int whalf = wv & 1;

  const float* q = qg + (size_t)pair * IMG;
  const float* k = kg + (size_t)pair * IMG;
  const float* v = vg + (size_t)pair * IMG;
  float* o = og + (size_t)pair * IMG;

  if (tid < 13)
    kh13[tid] = khg[c * 13 + tid];
  else if (tid < 26)
    kw13[tid - 13] = kwg[c * 13 + tid - 13];

  // Load: 1152 tasks of (2 rows x 4 cols) fp32 -> f16. Q,K -> normal +
  // transposed LDS; V -> transposed-packed dwords held in registers until
  // b2 (Q^T) dies.
  u32 vh[5][4];
#pragma unroll
  for (int it = 0; it < 5; ++it) {
    const int task = tid + it * 256;
    if (task < 1152) {
      const int g = task % 24, rs = task / 24;
      const int r0 = rs * 2, c0 = g * 4;
      const int src = r0 * NN + c0;
      const float4 qa = *(const float4*)(q + src);
      const float4 qb = *(const float4*)(q + src + NN);
      const float4 ka = *(const float4*)(k + src);
      const float4 kb = *(const float4*)(k + src + NN);
      const float4 va = *(const float4*)(v + src);
      const float4 vb = *(const float4*)(v + src + NN);
      *(uint2*)(b0 + r0 * LD + c0) = make_uint2(pk(qa.x, qa.y), pk(qa.z, qa.w));
      *(uint2*)(b0 + (r0 + 1) * LD + c0) = make_uint2(pk(qb.x, qb.y), pk(qb.z, qb.w));
      *(uint2*)(b1 + r0 * LD + c0) = make_uint2(pk(ka.x, ka.y), pk(ka.z, ka.w));
      *(uint2*)(b1 + (r0 + 1) * LD + c0) = make_uint2(pk(kb.x, kb.y), pk(kb.z, kb.w));
      // transpose-pack: dword at [col][r0] = f16(row r0) | f16(row r0+1)<<16
      *(u32*)(b2 + (c0 + 0) * LD + r0) = pk(qa.x, qb.x);
      *(u32*)(b2 + (c0 + 1) * LD + r0) = pk(qa.y, qb.y);
      *(u32*)(b2 + (c0 + 2) * LD + r0) = pk(qa.z, qb.z);
      *(u32*)(b2 + (c0 + 3) * LD + r0) = pk(qa.w, qb.w);
      *(u32*)(b3 + (c0 + 0) * LD + r0) = pk(ka.x, kb.x);
      *(u32*)(b3 + (c0 + 1) * LD + r0) = pk(ka.y, kb.y);
      *(u32*)(b3 + (c0 + 2) * LD + r0) = pk(ka.z, kb.z);
      *(u32*)(b3 + (c0 + 3) * LD + r0) = pk(ka.w, kb.w);
      vh[it][0] = pk(va.x, vb.x);
      vh[it][1] = pk(va.y, vb.y);
      vh[it][2] = pk(va.z, vb.z);
      vh[it][3] = pk(va.w, vb.w);
    }
  }
  __syncthreads();

  floatx4 acc[3][3];

  // Stage A: S_h = Q K^T -> softmax+band_h -> M_h (over b0)
  mm33(b0, b1, tr0, tc0, ln, quad, acc);
  softmax_band(acc, tr0, tc0, ln, quad, whalf, scrM, scrS, kh13, b0);

  // Stage C: S_w = Q^T K (A=Q^T, BT=K^T) -> softmax+band_w -> M_w (over b1)
  mm33(b2, b3, tr0, tc0, ln, quad, acc);
  __syncthreads();  // b2/b3 frag reads done -> V^T may overwrite b2
#pragma unroll
  for (int it = 0; it < 5; ++it) {
    const int task = tid + it * 256;
    if (task < 1152) {
      const int g = task % 24, rs = task / 24;
      const int r0 = rs * 2, c0 = g * 4;
#pragma unroll
      for (int j = 0; j < 4; ++j)
        *(u32*)(b2 + (c0 + j) * LD + r0) = vh[it][j];
    }
  }
  softmax_band(acc, tr0, tc0, ln, quad, whalf, scrM, scrS, kw13, b1);

  // Stage B: V1 = M_h V (A=b0, BT=V^T=b2) -> b3 (K^T dead)
  mm33(b0, b2, tr0, tc0, ln, quad, acc);
#pragma unroll
  for (int i = 0; i < 3; ++i)
#pragma unroll
    for (int v4 = 0; v4 < 4; ++v4) {
      const int R = tr0 + i * 16 + quad * 4 + v4;
#pragma unroll
      for (int j = 0; j < 3; ++j)
        b3[R * LD + (tc0 + j * 16 + ln)] = f2h(acc[i][j][v4]);
    }
  __syncthreads();

  // Stage D: Out = V1 M_w^T (A=b3, BT=b1) -> fp32 stage over dead b2+b3
  mm33(b3, b1, tr0, tc0, ln, quad, acc);
  __syncthreads();  // all waves done reading b3/b1 before ostage overwrites b2+b3
#pragma unroll
  for (int i = 0; i < 3; ++i)
#pragma unroll
    for (int v4 = 0; v4 < 4; ++v4) {
      const int R = tr0 + i * 16 + quad * 4 + v4;
#pragma unroll
      for (int j = 0; j < 3; ++j)
        ostage[R * OP + (tc0 + j * 16 + ln)] = acc[i][j][v4];
    }
  __syncthreads();
  // Coalesced fp32 store: 9216 floats, float4 per thread x 9 iters
#pragma unroll
  for (int it = 0; it < 9; ++it) {
    const int idx = (tid + it * 256) * 4;
    const int r = idx / NN, cg = idx % NN;
    *(float4*)(o + idx) = *(const float4*)(ostage + r * OP + cg);
  }
}

extern "C" void kernel_launch(void* const* d_in, const int* in_sizes, int n_in,
                              void* d_out, int out_size, void* d_ws, size_t ws_size,
                              hipStream_t stream) {
  (void)in_sizes; (void)n_in; (void)out_size; (void)d_ws; (void)ws_size;
  hipFuncSetAttribute(reinterpret_cast<const void*>(doc_kernel),
                      hipFuncAttributeMaxDynamicSharedMemorySize, SMEM_BYTES);
  doc_kernel<<<PAIRS, 256, SMEM_BYTES, stream>>>(
      (const float*)d_in[0], (const float*)d_in[1], (const float*)d_in[2],
      (const float*)d_in[3], (const float*)d_in[4], (float*)d_out);
}

// Round 5
// 266.816 us; speedup vs baseline: 1.0467x; 1.0467x over previous
//
#include <hip/hip_runtime.h>

// DynamicOversizeConv2d: per (b,c) pair [2048 total], 96x96 matrices:
//   M_h = softmax_rows(Q K^T) + band_h(c);  M_w = softmax_rows(Q^T K) + band_w(c)
//   Out = (M_h V) M_w^T
// Inputs fp32, output fp32, internal compute fp16 MFMA (absmax 0.031 vs 0.119).
// R5 restructure: 384 threads = 6 waves; wave w owns rows [16w,16w+16) of every
// stage -> softmax is wave-local (shfl-only), barriers 12 -> 5, occupancy
// 12 waves/CU (2 blocks x 6). Lane remap (g=t&3, rs=t%192/4) makes transposed
// LDS stores 2-way (free) instead of ~11-way, keeping 64B-coalesced global reads.
// LDS = 4 f16 tiles (96x104) + 26 floats = 79,976 B -> 2 blocks/CU.

typedef unsigned short u16;
typedef unsigned int u32;
typedef __attribute__((ext_vector_type(8))) _Float16 half8;
typedef __attribute__((ext_vector_type(4))) float floatx4;

#define NN 96
#define LD 104            // f16-tile row pitch (elems): 208 B = 16B-aligned rows
#define OP 100            // fp32 out-stage row pitch (floats)
#define NT 384
#define PAIRS 2048
#define IMG 9216
#define SMEM_BYTES 79976  // 4*96*104*2 + 26*4

__device__ __forceinline__ u16 f2h(float f) {
  union { _Float16 h; u16 u; } x;
  x.h = (_Float16)f;  // v_cvt_f16_f32 RNE
  return x.u;
}
__device__ __forceinline__ u32 pk(float lo, float hi) {
  return (u32)f2h(lo) | ((u32)f2h(hi) << 16);
}

// acc[j] (j=0..5) = row-stripe x all-cols: D[16w+quad*4+v][16j+ln].
// A row = arow (=16w+ln) of A-tile; BT rows 16j+ln. 3 k-steps of 32.
__device__ __forceinline__ void mm16(const u16* A, const u16* B, int arow,
                                     int ln, int quad, floatx4 acc[6]) {
#pragma unroll
  for (int j = 0; j < 6; ++j) acc[j] = (floatx4){0.f, 0.f, 0.f, 0.f};
#pragma unroll
  for (int ks = 0; ks < 3; ++ks) {
    const int kb = ks * 32 + quad * 8;
    const half8 a = *(const half8*)(A + arow * LD + kb);
    half8 b[6];
#pragma unroll
    for (int j = 0; j < 6; ++j)
      b[j] = *(const half8*)(B + (j * 16 + ln) * LD + kb);
#pragma unroll
    for (int j = 0; j < 6; ++j)
      acc[j] = __builtin_amdgcn_mfma_f32_16x16x32_f16(a, b[j], acc[j], 0, 0, 0);
  }
}

// Wave-local row softmax: row R = R0+quad*4+v lives in one quad across acc[0..5].
__device__ __forceinline__ void softmax_inplace(floatx4 acc[6]) {
#pragma unroll
  for (int v = 0; v < 4; ++v) {
    float m = acc[0][v];
#pragma unroll
    for (int j = 1; j < 6; ++j) m = fmaxf(m, acc[j][v]);
    m = fmaxf(m, __shfl_xor(m, 1));
    m = fmaxf(m, __shfl_xor(m, 2));
    m = fmaxf(m, __shfl_xor(m, 4));
    m = fmaxf(m, __shfl_xor(m, 8));
    float s = 0.f;
#pragma unroll
    for (int j = 0; j < 6; ++j) {
      const float e = __expf(acc[j][v] - m);
      acc[j][v] = e;
      s += e;
    }
    s += __shfl_xor(s, 1);
    s += __shfl_xor(s, 2);
    s += __shfl_xor(s, 4);
    s += __shfl_xor(s, 8);
    const float inv = __builtin_amdgcn_rcpf(s);
#pragma unroll
    for (int j = 0; j < 6; ++j) acc[j][v] *= inv;
  }
}

// Add band and store f16 stripe rows to D.
__device__ __forceinline__ void band_store(const floatx4 acc[6], int R0, int ln,
                                           int quad, const float* band13, u16* D) {
#pragma unroll
  for (int v = 0; v < 4; ++v) {
    const int R = R0 + quad * 4 + v;
#pragma unroll
    for (int j = 0; j < 6; ++j) {
      const int C = j * 16 + ln;
      const int off = C - R + 6;
      const float bnd = ((unsigned)off < 13u) ? band13[off] : 0.f;
      D[R * LD + C] = f2h(acc[j][v] + bnd);
    }
  }
}

extern "C" __global__ void __launch_bounds__(NT, 3)
doc_kernel(const float* __restrict__ qg, const float* __restrict__ kg,
           const float* __restrict__ vg, const float* __restrict__ khg,
           const float* __restrict__ kwg, float* __restrict__ og) {
  extern __shared__ char smem[];
  u16* b0 = (u16*)smem;       // Q   -> M_h
  u16* b1 = b0 + NN * LD;     // K   -> M_w
  u16* b2 = b1 + NN * LD;     // Q^T -> V^T -> (with b3) fp32 out stage
  u16* b3 = b2 + NN * LD;     // K^T -> V1
  float* kh13 = (float*)(b3 + NN * LD);
  float* kw13 = kh13 + 13;
  float* ostage = (float*)b2;  // 96 x OP fp32 = 38,400 B over b2+b3

  const int pair = blockIdx.x;
  const int c = pair & 255;
  const int tid = threadIdx.x;
  const int lane = tid & 63;
  const int wv = tid >> 6;      // 0..5
  const int quad = lane >> 4;
  const int ln = lane & 15;
  const int R0 = wv * 16;       // owned row stripe
  const int arow = R0 + ln;

  const float* q = qg + (size_t)pair * IMG;
  const float* k = kg + (size_t)pair * IMG;
  const float* v = vg + (size_t)pair * IMG;
  float* o = og + (size_t)pair * IMG;

  if (tid < 13)
    kh13[tid] = khg[c * 13 + tid];
  else if (tid < 26)
    kw13[tid - 13] = kwg[c * 13 + tid - 13];

  // Load 1152 tasks (= 3/thread) of (2 rows x 4 cols) fp32->f16.
  // Mapping: m=t/192 (col super), rs=(t%192)/4 (row pair), g=t&3 (col sub).
  // Wave = fixed m, rs spans 16, g spans 4 -> global 64B lines; transposed
  // store bank = (16(g&1)+rs)%32 -> 2-way (free).
  u32 vh[3][4];
#pragma unroll
  for (int it = 0; it < 3; ++it) {
    const int t = tid + it * NT;
    const int m = t / 192;
    const int rs = (t % 192) >> 2;
    const int g = t & 3;
    const int r0 = rs * 2;
    const int c0 = m * 16 + g * 4;
    const int src = r0 * NN + c0;
    const float4 qa = *(const float4*)(q + src);
    const float4 qb = *(const float4*)(q + src + NN);
    const float4 ka = *(const float4*)(k + src);
    const float4 kb = *(const float4*)(k + src + NN);
    const float4 va = *(const float4*)(v + src);
    const float4 vb = *(const float4*)(v + src + NN);
    *(uint2*)(b0 + r0 * LD + c0) = make_uint2(pk(qa.x, qa.y), pk(qa.z, qa.w));
    *(uint2*)(b0 + (r0 + 1) * LD + c0) = make_uint2(pk(qb.x, qb.y), pk(qb.z, qb.w));
    *(uint2*)(b1 + r0 * LD + c0) = make_uint2(pk(ka.x, ka.y), pk(ka.z, ka.w));
    *(uint2*)(b1 + (r0 + 1) * LD + c0) = make_uint2(pk(kb.x, kb.y), pk(kb.z, kb.w));
    // transposed: T[col][r0] = f16(row r0) | f16(row r0+1)<<16
    *(u32*)(b2 + (c0 + 0) * LD + r0) = pk(qa.x, qb.x);
    *(u32*)(b2 + (c0 + 1) * LD + r0) = pk(qa.y, qb.y);
    *(u32*)(b2 + (c0 + 2) * LD + r0) = pk(qa.z, qb.z);
    *(u32*)(b2 + (c0 + 3) * LD + r0) = pk(qa.w, qb.w);
    *(u32*)(b3 + (c0 + 0) * LD + r0) = pk(ka.x, kb.x);
    *(u32*)(b3 + (c0 + 1) * LD + r0) = pk(ka.y, kb.y);
    *(u32*)(b3 + (c0 + 2) * LD + r0) = pk(ka.z, kb.z);
    *(u32*)(b3 + (c0 + 3) * LD + r0) = pk(ka.w, kb.w);
    vh[it][0] = pk(va.x, vb.x);
    vh[it][1] = pk(va.y, vb.y);
    vh[it][2] = pk(va.z, vb.z);
    vh[it][3] = pk(va.w, vb.w);
  }
  __syncthreads();  // B1

  floatx4 acc[6];

  // Stage A: S_h stripe = Q(own rows) K^T -> wave-local softmax -> M_h into b0
  // (own stripe of b0 is read only by this wave -> no barrier needed).
  mm16(b0, b1, arow, ln, quad, acc);
  softmax_inplace(acc);
  band_store(acc, R0, ln, quad, kh13, b0);

  // Stage C: S_w stripe = Q^T(own rows) K; softmax now, store M_w after B2
  // (b1 is still being read by slower waves' stage A; b2 gets V^T).
  mm16(b2, b3, arow, ln, quad, acc);
  softmax_inplace(acc);
  __syncthreads();  // B2
  band_store(acc, R0, ln, quad, kw13, b1);
#pragma unroll
  for (int it = 0; it < 3; ++it) {
    const int t = tid + it * NT;
    const int m = t / 192;
    const int rs = (t % 192) >> 2;
    const int g = t & 3;
    const int r0 = rs * 2;
    const int c0 = m * 16 + g * 4;
#pragma unroll
    for (int j = 0; j < 4; ++j)
      *(u32*)(b2 + (c0 + j) * LD + r0) = vh[it][j];
  }
  __syncthreads();  // B3

  // Stage B: V1 stripe = M_h(own) V (BT = V^T in b2); store f16 to b3 own
  // stripe (self-read only in stage D -> no barrier).
  mm16(b0, b2, arow, ln, quad, acc);
#pragma unroll
  for (int v4 = 0; v4 < 4; ++v4) {
    const int R = R0 + quad * 4 + v4;
#pragma unroll
    for (int j = 0; j < 6; ++j)
      b3[R * LD + (j * 16 + ln)] = f2h(acc[j][v4]);
  }

  // Stage D: Out stripe = V1(own) M_w^T (BT = M_w in b1).
  mm16(b3, b1, arow, ln, quad, acc);
  __syncthreads();  // B4: everyone done reading b2 (stage B) / b3 (stage D)

  // fp32 out-stage over dead b2+b3, then coalesced float4 store.
#pragma unroll
  for (int v4 = 0; v4 < 4; ++v4) {
    const int R = R0 + quad * 4 + v4;
#pragma unroll
    for (int j = 0; j < 6; ++j)
      ostage[R * OP + (j * 16 + ln)] = acc[j][v4];
  }
  __syncthreads();  // B5
#pragma unroll
  for (int it = 0; it < 6; ++it) {
    const int idx = (tid + it * NT) * 4;
    const int r = idx / NN, cg = idx % NN;
    *(float4*)(o + idx) = *(const float4*)(ostage + r * OP + cg);
  }
}

extern "C" void kernel_launch(void* const* d_in, const int* in_sizes, int n_in,
                              void* d_out, int out_size, void* d_ws, size_t ws_size,
                              hipStream_t stream) {
  (void)in_sizes; (void)n_in; (void)out_size; (void)d_ws; (void)ws_size;
  hipFuncSetAttribute(reinterpret_cast<const void*>(doc_kernel),
                      hipFuncAttributeMaxDynamicSharedMemorySize, SMEM_BYTES);
  doc_kernel<<<PAIRS, NT, SMEM_BYTES, stream>>>(
      (const float*)d_in[0], (const float*)d_in[1], (const float*)d_in[2],
      (const float*)d_in[3], (const float*)d_in[4], (float*)d_out);
}